// Round 1
// baseline (1412.031 us; speedup 1.0000x reference)
//
#include <hip/hip_runtime.h>

#define BB    32
#define CDIM  256
#define TT    2048
#define NE    1024
#define NROWS (BB * TT)          // 65536
#define NELEM (BB * CDIM * TT)   // 16777216

// ---------------------------------------------------------------------------
// numpy pairwise sum of squares over 128 elements (stride in elements),
// replicating numpy's pairwise_sum: 8 partial accumulators r0..r7,
// r[j] = sum of x[j], x[8+j], ..., x[120+j], combined as
// ((r0+r1)+(r2+r3)) + ((r4+r5)+(r6+r7)).  fp contract OFF: numpy squares
// (rounded) then adds.
// ---------------------------------------------------------------------------
__device__ __forceinline__ float np_sq_sum128(const float* p, int stride) {
#pragma clang fp contract(off)
  float r[8];
#pragma unroll
  for (int j = 0; j < 8; j++) {
    float v = p[(size_t)j * stride];
    r[j] = v * v;
  }
  for (int i = 8; i < 128; i += 8) {
#pragma unroll
    for (int j = 0; j < 8; j++) {
      float v = p[(size_t)(i + j) * stride];
      float s = v * v;
      r[j] += s;
    }
  }
  return ((r[0] + r[1]) + (r[2] + r[3])) + ((r[4] + r[5]) + (r[6] + r[7]));
}

// e2[k] = sum_c codebook[k][c]^2, numpy pairwise order (256 = 128 + 128)
__global__ __launch_bounds__(256) void e2_kernel(const float* __restrict__ cb,
                                                 float* __restrict__ e2) {
#pragma clang fp contract(off)
  int k = blockIdx.x * 256 + threadIdx.x;
  if (k >= NE) return;
  const float* p = cb + (size_t)k * CDIM;
  float h0 = np_sq_sum128(p, 1);
  float h1 = np_sq_sum128(p + 128, 1);
  e2[k] = h0 + h1;
}

// z2[n] = sum_c z[b][c][t]^2 with n = b*TT + t (strided by TT in c)
__global__ __launch_bounds__(256) void z2_kernel(const float* __restrict__ z,
                                                 float* __restrict__ z2) {
#pragma clang fp contract(off)
  int n = blockIdx.x * 256 + threadIdx.x;
  if (n >= NROWS) return;
  int b = n >> 11;          // / TT
  int t = n & (TT - 1);
  const float* p = z + (size_t)b * CDIM * TT + t;
  float h0 = np_sq_sum128(p, TT);
  float h1 = np_sq_sum128(p + (size_t)128 * TT, TT);
  z2[n] = h0 + h1;
}

// ---------------------------------------------------------------------------
// Distance + argmin.  Block = 256 threads (16x16), tile = 64 rows (one b,
// 64 consecutive t) x 64 codes per chunk, K staged 32 at a time in LDS.
// d = fl( fl(z2 + e2) - fl(2*G) ), G accumulated sequentially over k=0..255
// in a single fp32 accumulator with mul-then-add (contract off), matching
// the np reference's quantization as closely as possible.  Ties -> lowest
// index (numpy argmin first-occurrence semantics).
// ---------------------------------------------------------------------------
__global__ __launch_bounds__(256) void dist_argmin_kernel(
    const float* __restrict__ z, const float* __restrict__ cb,
    const float* __restrict__ z2, const float* __restrict__ e2,
    int* __restrict__ out_idx) {
#pragma clang fp contract(off)
  __shared__ float zs[32][64];      // [k][row]   8 KiB, conflict-free
  __shared__ float es[32][68];      // [k][code]  padded +4 (store 4-way max)
  __shared__ float rv[64][17];
  __shared__ int   ri[64][17];

  const int bid = blockIdx.x;
  const int b   = bid >> 5;              // 32 t-tiles per b
  const int t0  = (bid & 31) << 6;
  const int tid = threadIdx.x;
  const int tx  = tid & 15;
  const int ty  = tid >> 4;

  const float* zb = z + (size_t)b * CDIM * TT + t0;

  float bv[4];
  int   bi[4];
#pragma unroll
  for (int r = 0; r < 4; r++) { bv[r] = __builtin_inff(); bi[r] = 0; }

  float z2r[4];
#pragma unroll
  for (int r = 0; r < 4; r++) z2r[r] = z2[b * TT + t0 + ty * 4 + r];

  for (int n0 = 0; n0 < NE; n0 += 64) {
    float acc[4][4];
#pragma unroll
    for (int r = 0; r < 4; r++)
#pragma unroll
      for (int j = 0; j < 4; j++) acc[r][j] = 0.0f;

    for (int kc = 0; kc < CDIM; kc += 32) {
      __syncthreads();
      {  // stage z tile: 32 k x 64 rows; lanes vary t -> coalesced
        int t4 = tid & 63;
        int c4 = tid >> 6;  // 0..3
#pragma unroll
        for (int i = 0; i < 8; i++) {
          int k = c4 * 8 + i;
          zs[k][t4] = zb[(size_t)(kc + k) * TT + t4];
        }
      }
      {  // stage codebook tile: 32 k x 64 codes; lanes vary c -> coalesced
        int cs = tid & 31;
        int q  = tid >> 5;  // 0..7
#pragma unroll
        for (int i = 0; i < 8; i++) {
          int code = q * 8 + i;
          es[cs][code] = cb[(size_t)(n0 + code) * CDIM + kc + cs];
        }
      }
      __syncthreads();
#pragma unroll
      for (int k = 0; k < 32; k++) {
        float4 zv = *(const float4*)&zs[k][ty * 4];
        float4 ev = *(const float4*)&es[k][tx * 4];
        float za[4] = {zv.x, zv.y, zv.z, zv.w};
        float ea[4] = {ev.x, ev.y, ev.z, ev.w};
#pragma unroll
        for (int r = 0; r < 4; r++)
#pragma unroll
          for (int j = 0; j < 4; j++) {
            float p = za[r] * ea[j];   // no FMA: match np mul-then-add
            acc[r][j] += p;
          }
      }
    }
    // epilogue: quantize like np and fold into running argmin
#pragma unroll
    for (int r = 0; r < 4; r++)
#pragma unroll
      for (int j = 0; j < 4; j++) {
        int   code = n0 + tx * 4 + j;
        float tg   = 2.0f * acc[r][j];
        float s    = z2r[r] + e2[code];
        float d    = s - tg;
        if (d < bv[r]) { bv[r] = d; bi[r] = code; }  // codes ascend -> first-min
      }
  }

  __syncthreads();
#pragma unroll
  for (int r = 0; r < 4; r++) {
    rv[ty * 4 + r][tx] = bv[r];
    ri[ty * 4 + r][tx] = bi[r];
  }
  __syncthreads();
  if (tid < 64) {
    float v  = rv[tid][0];
    int   ii = ri[tid][0];
#pragma unroll
    for (int x = 1; x < 16; x++) {
      float v2 = rv[tid][x];
      int   i2 = ri[tid][x];
      if (v2 < v || (v2 == v && i2 < ii)) { v = v2; ii = i2; }
    }
    out_idx[b * TT + t0 + tid] = ii;
  }
}

// ---------------------------------------------------------------------------
// Gather z_q, straight-through output fl(z + fl(zq - z)), loss accumulation
// (fp32 squares like np, summed in double -> error << threshold)
// ---------------------------------------------------------------------------
__global__ __launch_bounds__(256) void zq_loss_kernel(
    const float* __restrict__ z, const float* __restrict__ cb,
    const int* __restrict__ idx, float* __restrict__ zq_out,
    double* __restrict__ loss_acc) {
#pragma clang fp contract(off)
  __shared__ double sh[256];
  double local = 0.0;
  int stride = gridDim.x * blockDim.x;
  for (int i = blockIdx.x * blockDim.x + threadIdx.x; i < NELEM; i += stride) {
    int t = i & (TT - 1);
    int c = (i >> 11) & (CDIM - 1);
    int b = i >> 19;
    int n = (b << 11) | t;
    float zq   = cb[(size_t)idx[n] * CDIM + c];
    float zv   = z[i];
    float diff = zq - zv;
    zq_out[i]  = zv + diff;          // straight-through, np op order
    float sq   = diff * diff;        // square rounded in fp32 like np
    local += (double)sq;
  }
  sh[threadIdx.x] = local;
  __syncthreads();
  for (int s = 128; s > 0; s >>= 1) {
    if (threadIdx.x < s) sh[threadIdx.x] += sh[threadIdx.x + s];
    __syncthreads();
  }
  if (threadIdx.x == 0) atomicAdd(loss_acc, sh[0]);
}

// one-hot scatter + indices output (as float) + histogram
__global__ __launch_bounds__(256) void scatter_kernel(
    const int* __restrict__ idx, float* __restrict__ onehot,
    float* __restrict__ idx_out, int* __restrict__ cnt) {
  int n = blockIdx.x * 256 + threadIdx.x;
  if (n >= NROWS) return;
  int k = idx[n];
  onehot[(size_t)n * NE + k] = 1.0f;
  idx_out[n] = (float)k;
  atomicAdd(&cnt[k], 1);
}

__global__ __launch_bounds__(1024) void finalize_kernel(
    const int* __restrict__ cnt, const double* __restrict__ loss_acc,
    float* __restrict__ out_loss, float* __restrict__ out_perp) {
#pragma clang fp contract(off)
  __shared__ float sh[1024];
  int t = threadIdx.x;
  float em = (float)cnt[t] / 65536.0f;       // exact: int / 2^16
  sh[t] = em * logf(em + 1e-10f);
  __syncthreads();
  for (int s = 512; s > 0; s >>= 1) {
    if (t < s) sh[t] += sh[t + s];
    __syncthreads();
  }
  if (t == 0) {
    *out_perp = expf(-sh[0]);
    double m  = *loss_acc / (double)NELEM;
    float mf  = (float)m;
    float bt  = 0.25f * mf;
    *out_loss = mf + bt;                     // loss = m + BETA*m (same array)
  }
}

// ---------------------------------------------------------------------------
extern "C" void kernel_launch(void* const* d_in, const int* in_sizes, int n_in,
                              void* d_out, int out_size, void* d_ws,
                              size_t ws_size, hipStream_t stream) {
  const float* z  = (const float*)d_in[0];
  const float* cb = (const float*)d_in[1];
  float* out = (float*)d_out;

  // workspace layout
  int*    ws_idx  = (int*)d_ws;              // 65536 ints
  int*    ws_cnt  = ws_idx + NROWS;          // 1024 ints
  double* ws_loss = (double*)(ws_cnt + NE);  // byte off 266240, 8-aligned
  float*  ws_e2   = (float*)(ws_loss + 1);   // 1024 floats
  float*  ws_z2   = ws_e2 + NE;              // 65536 floats

  // output layout (flat fp32 concat, reference return order)
  float* out_loss = out;
  float* out_zq   = out + 1;
  float* out_perp = out + 1 + (size_t)NELEM;
  float* out_oh   = out + 2 + (size_t)NELEM;
  float* out_idx  = out + 2 + (size_t)NELEM + (size_t)NROWS * NE;

  // zero counters/accumulator and the one-hot region (re-poisoned each call)
  hipMemsetAsync(ws_cnt, 0, NE * sizeof(int) + sizeof(double), stream);
  hipMemsetAsync(out_oh, 0, (size_t)NROWS * NE * sizeof(float), stream);

  e2_kernel<<<NE / 256, 256, 0, stream>>>(cb, ws_e2);
  z2_kernel<<<NROWS / 256, 256, 0, stream>>>(z, ws_z2);
  dist_argmin_kernel<<<1024, 256, 0, stream>>>(z, cb, ws_z2, ws_e2, ws_idx);
  zq_loss_kernel<<<2048, 256, 0, stream>>>(z, cb, ws_idx, out_zq, ws_loss);
  scatter_kernel<<<NROWS / 256, 256, 0, stream>>>(ws_idx, out_oh, out_idx,
                                                  ws_cnt);
  finalize_kernel<<<1, 1024, 0, stream>>>(ws_cnt, ws_loss, out_loss, out_perp);
}